// Round 12
// baseline (8801.903 us; speedup 1.0000x reference)
//
#include <hip/hip_runtime.h>

#define Hd 1024
#define Sd 4096
#define G4 4096   // 4*H

typedef __attribute__((ext_vector_type(8))) short    bf16x8;
typedef __attribute__((ext_vector_type(8))) unsigned short u16x8;
typedef __attribute__((ext_vector_type(4))) unsigned short u16x4;
typedef __attribute__((ext_vector_type(4))) unsigned u32x4;
typedef __attribute__((ext_vector_type(4))) float    f32x4;

// ---- ws layout (bytes) ----
#define WS_WHH_F 0u                 // 4096*1024*2 = 8388608
#define WS_WIH_F 8388608u           // 8388608
#define WS_EMB_F 16777216u          // 8388608 (dead after gemm_k; hrec reuses its head)
#define WS_HREC  16777216u          // 2 buffers x 256 chunks x 16B = 8192
#define WS_XG    25165824u          // 4096*4096*2 = 33554432
#define WS_BIAS  58720256u          // 4096*4 = 16384
                                    // NOTE: t=4095's xg t+1 prefetch reads the bias
                                    // region (in-bounds of d_ws, values unused).

__device__ __forceinline__ float b2f(unsigned short u) {
    return __uint_as_float(((unsigned)u) << 16);
}
__device__ __forceinline__ unsigned short f2b(float f) {
    unsigned u = __float_as_uint(f);
    unsigned r = u + 0x7fffu + ((u >> 16) & 1u);   // RNE
    return (unsigned short)(r >> 16);
}
__device__ __forceinline__ float sigmoid_fast(float x) {
    return 1.f / (1.f + __expf(-x));   // inf-safe at both ends
}
__device__ __forceinline__ float tanh_fast(float x) {
    float e = __expf(2.f * fabsf(x));  // inf-safe: 2/(inf+1)=0 -> +-1
    return copysignf(1.f - 2.f / (e + 1.f), x);
}

// Pack a [R x 1024] f32 matrix (optionally row-gathered by idx) into MFMA
// A-fragment order: chunk(rb,kb) = 64 lanes x 8 bf16,
// elem(l,j) = src[rb*16 + (l&15)][kb*32 + (l>>4)*8 + j]
__global__ void pack_frag(const float* __restrict__ src, const int* __restrict__ idx,
                          unsigned short* __restrict__ dst) {
    const int rb = blockIdx.x;       // 0..255
    const int kb = blockIdx.y;       // 0..31
    const int l  = threadIdx.x;      // 0..63
    int row = rb * 16 + (l & 15);
    if (idx) row = idx[row];
    const float* s = src + (size_t)row * Hd + kb * 32 + ((l >> 4) & 3) * 8;
    float4 f0 = *(const float4*)s;
    float4 f1 = *(const float4*)(s + 4);
    u16x8 v;
    v[0]=f2b(f0.x); v[1]=f2b(f0.y); v[2]=f2b(f0.z); v[3]=f2b(f0.w);
    v[4]=f2b(f1.x); v[5]=f2b(f1.y); v[6]=f2b(f1.z); v[7]=f2b(f1.w);
    *(u16x8*)(dst + ((size_t)(rb * 32 + kb) * 64 + l) * 8) = v;
}

// W_hh packing for the wave-local cell: block rb = role*8 + w holds rows
// r = gate*4 + j  ->  global row gate*1024 + role*32 + w*4 + j.
// After MFMA, a wave holds ALL 4 gates for its 4 h-indices.
__global__ void pack_whh(const float* __restrict__ src, unsigned short* __restrict__ dst) {
    const int rb = blockIdx.x;       // 0..255 = role*8 + w
    const int kb = blockIdx.y;       // 0..31
    const int l  = threadIdx.x;      // 0..63
    const int role = rb >> 3, w = rb & 7;
    const int r = l & 15, gate = r >> 2, j = r & 3;
    const int row = (gate << 10) + (role << 5) + (w << 2) + j;
    const float* s = src + (size_t)row * Hd + kb * 32 + ((l >> 4) & 3) * 8;
    float4 f0 = *(const float4*)s;
    float4 f1 = *(const float4*)(s + 4);
    u16x8 v;
    v[0]=f2b(f0.x); v[1]=f2b(f0.y); v[2]=f2b(f0.z); v[3]=f2b(f0.w);
    v[4]=f2b(f1.x); v[5]=f2b(f1.y); v[6]=f2b(f1.z); v[7]=f2b(f1.w);
    *(u16x8*)(dst + ((size_t)(rb * 32 + kb) * 64 + l) * 8) = v;
}

__global__ void init_k(const float* __restrict__ bih, const float* __restrict__ bhh,
                       float* __restrict__ bias) {
    const int i = blockIdx.x * 256 + threadIdx.x;   // 0..4095
    bias[i] = bih[i] + bhh[i];
}

// zero BOTH hrec buffers (tags 0; garbage could alias a future tag).
__global__ void zero_hrec_k(unsigned* __restrict__ hrec) {
    hrec[blockIdx.x * 256 + threadIdx.x] = 0u;      // 2048 dwords
}

// xg[s][n] = sum_k embs[s][k]*W_ih[n][k] + bias[n], bf16 out.
__global__ __launch_bounds__(256, 2)
void gemm_k(const unsigned short* __restrict__ Af, const unsigned short* __restrict__ Bf,
            const float* __restrict__ bias, unsigned short* __restrict__ xg) {
    const int w = threadIdx.x >> 6, l = threadIdx.x & 63;
    const int wid = blockIdx.x * 4 + w;      // 0..4095
    const int mg = wid >> 6;                 // 0..63
    const int ng = wid & 63;                 // 0..63

    f32x4 acc[4][4] = {};
    for (int kb = 0; kb < 32; ++kb) {
        bf16x8 a[4], b[4];
#pragma unroll
        for (int mi = 0; mi < 4; ++mi)
            a[mi] = *(const bf16x8*)(Af + (((size_t)(mg * 4 + mi) * 32 + kb) * 64 + l) * 8);
#pragma unroll
        for (int ni = 0; ni < 4; ++ni)
            b[ni] = *(const bf16x8*)(Bf + (((size_t)(ng * 4 + ni) * 32 + kb) * 64 + l) * 8);
#pragma unroll
        for (int mi = 0; mi < 4; ++mi)
#pragma unroll
            for (int ni = 0; ni < 4; ++ni)
                acc[mi][ni] = __builtin_amdgcn_mfma_f32_16x16x32_bf16(a[mi], b[ni], acc[mi][ni], 0, 0, 0);
    }
    const int r4 = (l >> 4) * 4, c = l & 15;
#pragma unroll
    for (int ni = 0; ni < 4; ++ni) {
        const int col = ng * 64 + ni * 16 + c;
        const float bv = bias[col];
#pragma unroll
        for (int mi = 0; mi < 4; ++mi) {
            const int rowb = mg * 64 + mi * 16 + r4;
#pragma unroll
            for (int i = 0; i < 4; ++i)
                xg[(size_t)(rowb + i) * G4 + col] = f2b(acc[mi][ni][i] + bv);
        }
    }
}

// Persistent LSTM scan. 32 WGs x 512 thr (8 waves). WG r owns h[r*32, r*32+32);
// wave w owns h-indices r*32+w*4 .. +4, holding ALL 4 gates for them (16 rows,
// 32 MFMAs, W_hh in 128 VGPRs). Wave-local cell (per-wave LDS bounce, no
// cross-wave barrier after MFMA); each wave publishes its chunk immediately.
// h_sw is DOUBLE-BUFFERED: stage(u) can only start after poll(u) succeeds,
// which implies all waves published u-1, hence finished reading buffer u&1
// two steps ago -> no WAR, and only ONE s_barrier per step (stage->read).
// Transport (r4/r11-proven): 256 dual-tagged 16B chunks at LLC scope (sc0 sc1),
// drained single-sample poll with s_sleep(12) phase offset. Waves 4-7 skip
// polling. No dangling VMEM anywhere.
__global__ __launch_bounds__(512, 2)
void scan_k(const unsigned short* __restrict__ Wf, const unsigned short* __restrict__ xg,
            unsigned* __restrict__ hrec, float* __restrict__ out) {
    __shared__ unsigned h_sw[2][512];     // double-buffered h (1024 bf16 each)
    __shared__ float g_w[128];            // per-wave gate scratch [wave][16]

    const int role = blockIdx.x;          // 0..31
    const int tid  = threadIdx.x;         // 0..511
    const int w = tid >> 6, l = tid & 63;
    const int rb = (role << 3) + w;       // this wave's row-block in pack_whh order

    bf16x8 wfrag[32];                     // 128 VGPRs of W_hh
#pragma unroll
    for (int kb = 0; kb < 32; ++kb)
        wfrag[kb] = *(const bf16x8*)(Wf + (((size_t)rb * 32 + kb) * 64 + l) * 8);

    float c_reg = 0.f;                    // lanes l<4: cell state for h-idx role*32+w*4+l
    const int hoff = ((l >> 4) & 3) * 8;  // bf16 offset within each 32-chunk of h
    const int hout = (role << 5) + (w << 2);            // this wave's 4 h-indices
    const int xbase = ((l >> 4) << 10) + hout;          // xg row for lane's gate

    // xg t=0 prefetch (plain loads; compiler-managed waits)
    u16x4 xv = {0, 0, 0, 0};
    if ((l & 15) == 0)
        xv = *(const u16x4*)(xg + xbase);

    for (int t = 0; t < Sd; ++t) {
        const unsigned tt = (unsigned)t;

        // ---- waves 0-3: poll own chunk (drained, phase-offset), stage to LDS ----
        if (tid < 256) {
            const unsigned* gp = hrec + (t & 1) * 1024 + tid * 4;
            u32x4 pA;
            __builtin_amdgcn_s_sleep(12);   // phase offset: sample 1 usually fresh
            int guard = 0;
            while (true) {
                asm volatile("global_load_dwordx4 %0, %1, off sc0 sc1\n\ts_waitcnt vmcnt(0)"
                             : "=v"(pA) : "v"(gp) : "memory");
                __builtin_amdgcn_sched_barrier(0);
                if (!__any((pA[1] != tt) | (pA[3] != tt))) break;
                if (++guard > 65536) break;   // bounded: wrong, never hang
                __builtin_amdgcn_s_sleep(1);
            }
            h_sw[t & 1][tid * 2]     = pA[0];
            h_sw[t & 1][tid * 2 + 1] = pA[2];
            asm volatile("s_waitcnt lgkmcnt(0)" ::: "memory");
        }
        __builtin_amdgcn_s_barrier();                          // B1 (only barrier/step)
        __builtin_amdgcn_sched_barrier(0);

        // ---- 32 MFMAs: 4 interleaved 8-deep chains ----
        const unsigned short* h_ss = (const unsigned short*)h_sw[t & 1];
        f32x4 ac0 = {0,0,0,0}, ac1 = {0,0,0,0}, ac2 = {0,0,0,0}, ac3 = {0,0,0,0};
#pragma unroll
        for (int kb = 0; kb < 32; kb += 4) {
            bf16x8 h0 = *(const bf16x8*)(h_ss + (kb + 0) * 32 + hoff);
            bf16x8 h1 = *(const bf16x8*)(h_ss + (kb + 1) * 32 + hoff);
            bf16x8 h2 = *(const bf16x8*)(h_ss + (kb + 2) * 32 + hoff);
            bf16x8 h3 = *(const bf16x8*)(h_ss + (kb + 3) * 32 + hoff);
            ac0 = __builtin_amdgcn_mfma_f32_16x16x32_bf16(wfrag[kb + 0], h0, ac0, 0, 0, 0);
            ac1 = __builtin_amdgcn_mfma_f32_16x16x32_bf16(wfrag[kb + 1], h1, ac1, 0, 0, 0);
            ac2 = __builtin_amdgcn_mfma_f32_16x16x32_bf16(wfrag[kb + 2], h2, ac2, 0, 0, 0);
            ac3 = __builtin_amdgcn_mfma_f32_16x16x32_bf16(wfrag[kb + 3], h3, ac3, 0, 0, 0);
        }
        f32x4 acc = (ac0 + ac1) + (ac2 + ac3);
        // (B replicated across all 16 cols -> every lane in a 16-group holds the
        //  same 4 row-results; rows r0..r0+3 = gate (l>>4), j 0..3 of this wave.)

        // ---- wave-local gate combine: lanes 0,16,32,48 write 4 gates x 4 j ----
        if ((l & 15) == 0) {
            f32x4 gv;
#pragma unroll
            for (int i = 0; i < 4; ++i)
                gv[i] = acc[i] + b2f(xv[i]);
            *(f32x4*)&g_w[(w << 4) + ((l >> 4) << 2)] = gv;   // slot r = gate*4+j
        }
        // same-wave LDS RAW: compiler inserts lgkmcnt before the reads below.

        // ---- wave-local LSTM cell: lane j (0..3) handles h-idx hout+j ----
        float h = 0.f; unsigned short hbv = 0;
        if (l < 4) {
            float iv = sigmoid_fast(g_w[(w << 4) + l]);
            float fv = sigmoid_fast(g_w[(w << 4) + 4 + l]);
            float gg = tanh_fast  (g_w[(w << 4) + 8 + l]);
            float ov = sigmoid_fast(g_w[(w << 4) + 12 + l]);
            float c = fv * c_reg + iv * gg;
            c_reg = c;
            h = ov * tanh_fast(c);
            hbv = f2b(h);
        }
        // ---- publish chunk rb = {h0|h1, tag, h2|h3, tag} (lane 0) ----
        const unsigned u0 = (unsigned)hbv;
        const unsigned u1 = (unsigned)__shfl((int)u0, 1, 64);
        const unsigned u2 = (unsigned)__shfl((int)u0, 2, 64);
        const unsigned u3 = (unsigned)__shfl((int)u0, 3, 64);
        if (l == 0) {
            const unsigned tag = tt + 1u;
            u32x4 val = {u0 | (u1 << 16), tag, u2 | (u3 << 16), tag};
            unsigned* dst = hrec + ((t + 1) & 1) * 1024 + rb * 4;
            asm volatile("global_store_dwordx4 %0, %1, off sc0 sc1"
                         :: "v"(dst), "v"(val) : "memory");
        }
        // out[] and next-step xg AFTER the publish (off the critical path)
        if (l < 4) {
            out[(size_t)Hd + (size_t)t * Hd + hout + l] = h;   // outs[t]
            if (t == Sd - 1) out[hout + l] = h;                // final h
        }
        if ((l & 15) == 0)
            xv = *(const u16x4*)(xg + (size_t)(t + 1) * G4 + xbase);
        // fire-and-forget stores: drained by the next poll's vmcnt(0) (waves 0-3)
        // or by HW retirement (waves 4-7; vmcnt backpressure only).
    }
}

extern "C" void kernel_launch(void* const* d_in, const int* in_sizes, int n_in,
                              void* d_out, int out_size, void* d_ws, size_t ws_size,
                              hipStream_t stream) {
    (void)in_sizes; (void)n_in; (void)out_size; (void)ws_size;
    const int*   x   = (const int*)  d_in[0];
    const float* emb = (const float*)d_in[1];
    const float* Wih = (const float*)d_in[2];
    const float* Whh = (const float*)d_in[3];
    const float* bih = (const float*)d_in[4];
    const float* bhh = (const float*)d_in[5];
    float* out = (float*)d_out;

    char* ws = (char*)d_ws;
    unsigned short* whh_f = (unsigned short*)(ws + WS_WHH_F);
    unsigned short* wih_f = (unsigned short*)(ws + WS_WIH_F);
    unsigned short* emb_f = (unsigned short*)(ws + WS_EMB_F);
    unsigned short* xgp   = (unsigned short*)(ws + WS_XG);
    float*          bias  = (float*)        (ws + WS_BIAS);
    unsigned*       hrec  = (unsigned*)      (ws + WS_HREC);

    init_k     <<<16, 256, 0, stream>>>(bih, bhh, bias);
    pack_whh   <<<dim3(256, 32), 64, 0, stream>>>(Whh, whh_f);
    pack_frag  <<<dim3(256, 32), 64, 0, stream>>>(Wih, nullptr, wih_f);
    pack_frag  <<<dim3(256, 32), 64, 0, stream>>>(emb, x,       emb_f);
    gemm_k     <<<1024, 256, 0, stream>>>(emb_f, wih_f, bias, xgp);
    zero_hrec_k<<<8, 256, 0, stream>>>(hrec);          // after gemm: hrec aliases emb_f
    scan_k     <<<32, 512, 0, stream>>>(whh_f, xgp, hrec, out);
}